// Round 8
// baseline (253.051 us; speedup 1.0000x reference)
//
#include <hip/hip_runtime.h>

#define B_ROWS 4096
#define N_COLS 8192
#define BLOCK  256
#define F4_PER_ROW (N_COLS / 4)   // 2048 float4 per row
#define ISSUES 8                  // DMA issues per wave per input (512 f4 / 64 lanes)
#define CPOL_NT 2                 // gfx94x/gfx950 cpol: bit1 = NT (no L3 allocate on miss)

// R1-R7 journal:
//  - compiler clamps register-load MLP to ~2/wave regardless of source
//    structure, launch_bounds, sched_barrier (R2-R4, all neutral).
//  - R5: global_load_lds DMA gives true 16-deep per-wave queues; neutral at
//    the time because the wall was elsewhere.
//  - R7: non-temporal loads (skip L3 allocation on miss; labels stays
//    L3-resident, preds streams from HBM) cut the row kernel ~99 -> ~73 us.
//    The wall WAS Infinity-Cache fill/eviction traffic.
//  - R8: combine both — 16-deep DMA staging with NT cpol (aux=2), so the
//    now-unthrottled HBM stream also gets queue depth.
typedef const __attribute__((address_space(1))) void* gas_ptr;
typedef __attribute__((address_space(3))) void* las_ptr;

__global__ __launch_bounds__(BLOCK) void row_pearson_kernel(
    const float* __restrict__ preds,
    const float* __restrict__ labels,
    float* __restrict__ row_loss)
{
    __shared__ float4 sX[F4_PER_ROW];   // 32 KB
    __shared__ float4 sY[F4_PER_ROW];   // 32 KB
    __shared__ float partials[4][5];

    const int row  = blockIdx.x;
    const int tid  = threadIdx.x;
    const int w    = tid >> 6;
    const int lane = tid & 63;

    const float4* p4 = reinterpret_cast<const float4*>(preds  + (size_t)row * N_COLS);
    const float4* l4 = reinterpret_cast<const float4*>(labels + (size_t)row * N_COLS);

    // Stage: 16 async DMA issues per wave (16 KB in flight), NT cache policy.
    // Wave w covers float4 indices [w*512, (w+1)*512); LDS dst is
    // wave-uniform base + lane*16 (m104/m108), matching this layout exactly.
    #pragma unroll
    for (int i = 0; i < ISSUES; ++i) {
        const int g = (w << 9) + (i << 6) + lane;
        __builtin_amdgcn_global_load_lds((gas_ptr)(p4 + g), (las_ptr)(sX + g), 16, 0, CPOL_NT);
        __builtin_amdgcn_global_load_lds((gas_ptr)(l4 + g), (las_ptr)(sY + g), 16, 0, CPOL_NT);
    }
    __syncthreads();   // single vmcnt drain + barrier

    // Read back own quarter-row from LDS (ds_read_b128, contiguous, no
    // bank conflicts) and accumulate the 5 sums.
    float sx = 0.f, sy = 0.f, sxy = 0.f, sxx = 0.f, syy = 0.f;
    #pragma unroll
    for (int i = 0; i < ISSUES; ++i) {
        const int g = (w << 9) + (i << 6) + lane;
        const float4 a = sX[g];
        const float4 b = sY[g];
        sx  += a.x + a.y + a.z + a.w;
        sy  += b.x + b.y + b.z + b.w;
        sxy += a.x * b.x + a.y * b.y + a.z * b.z + a.w * b.w;
        sxx += a.x * a.x + a.y * a.y + a.z * a.z + a.w * a.w;
        syy += b.x * b.x + b.y * b.y + b.z * b.z + b.w * b.w;
    }

    // 64-lane wave reduction (wave = 64 on gfx950).
    #pragma unroll
    for (int off = 32; off > 0; off >>= 1) {
        sx  += __shfl_down(sx,  off);
        sy  += __shfl_down(sy,  off);
        sxy += __shfl_down(sxy, off);
        sxx += __shfl_down(sxx, off);
        syy += __shfl_down(syy, off);
    }

    if (lane == 0) {
        partials[w][0] = sx;  partials[w][1] = sy;  partials[w][2] = sxy;
        partials[w][3] = sxx; partials[w][4] = syy;
    }
    __syncthreads();

    if (tid == 0) {
        float tx = 0.f, ty = 0.f, txy = 0.f, txx = 0.f, tyy = 0.f;
        #pragma unroll
        for (int v = 0; v < 4; ++v) {
            tx  += partials[v][0]; ty  += partials[v][1]; txy += partials[v][2];
            txx += partials[v][3]; tyy += partials[v][4];
        }
        const float Nf  = (float)N_COLS;
        const float num = Nf * txy - tx * ty;
        const float den = sqrtf((Nf * txx - tx * tx) * (Nf * tyy - ty * ty));
        row_loss[row] = 1.0f - num / den;
    }
}

// Reduce 4096 per-row losses to the mean. Single block.
__global__ __launch_bounds__(BLOCK) void mean_kernel(
    const float* __restrict__ row_loss,
    float* __restrict__ out)
{
    const int tid = threadIdx.x;

    float s = 0.f;
    #pragma unroll
    for (int i = 0; i < B_ROWS / BLOCK; ++i)
        s += row_loss[tid + i * BLOCK];

    #pragma unroll
    for (int off = 32; off > 0; off >>= 1)
        s += __shfl_down(s, off);

    __shared__ float smem[4];
    const int wave = tid >> 6;
    const int lane = tid & 63;
    if (lane == 0) smem[wave] = s;
    __syncthreads();

    if (tid == 0) {
        float t = smem[0] + smem[1] + smem[2] + smem[3];
        out[0] = t / (float)B_ROWS;
    }
}

extern "C" void kernel_launch(void* const* d_in, const int* in_sizes, int n_in,
                              void* d_out, int out_size, void* d_ws, size_t ws_size,
                              hipStream_t stream) {
    const float* preds  = (const float*)d_in[0];
    const float* labels = (const float*)d_in[1];
    float* row_loss = (float*)d_ws;      // 4096 floats of scratch
    float* out      = (float*)d_out;

    row_pearson_kernel<<<B_ROWS, BLOCK, 0, stream>>>(preds, labels, row_loss);
    mean_kernel<<<1, BLOCK, 0, stream>>>(row_loss, out);
}

// Round 9
// 247.515 us; speedup vs baseline: 1.0224x; 1.0224x over previous
//
#include <hip/hip_runtime.h>

#define B_ROWS 4096
#define N_COLS 8192
#define BLOCK  256
#define F4_PER_ROW (N_COLS / 4)   // 2048 float4 per row
#define VPT    (F4_PER_ROW / BLOCK)  // 8 float4 per thread per input

typedef float vfloat4 __attribute__((ext_vector_type(4)));

// Journal R1-R8:
//  - R2-R4: compiler clamps register-load MLP to ~2/wave; launch_bounds,
//    sched_barrier all neutral. 2.7 TB/s effective.
//  - R5/R8: 16-deep global_load_lds DMA queues (128 KB/CU in flight) do NOT
//    beat 2-deep register loads -> service-rate wall, not latency.
//  - R7 WIN: non-temporal loads (no L3 allocation on miss) 99 -> ~71 us row.
//    The pre-NT wall was Infinity-Cache fill/eviction traffic.
//  - Post-NT we sit at ~14 GB/s/CU read service (3.8 TB/s chip) vs the m13
//    load-stream ceiling of ~10 B/cyc/CU (6.3 TB/s). Remaining structural
//    difference vs m13's copy: our waves interleave TWO base pointers at
//    identical offsets (x,y,x,y...) -> paired hits on the same L2 channel /
//    IC slice / HBM channel, 16B effective run-length per stream.
//  - R9 experiment: single-stream phases. Phase 1 stages the preds row into
//    LDS (one global stream, 8KB/wave unit-stride bursts); phase 2 streams
//    labels and computes against LDS.
__global__ __launch_bounds__(BLOCK) void row_pearson_kernel(
    const float* __restrict__ preds,
    const float* __restrict__ labels,
    float* __restrict__ row_loss)
{
    __shared__ float4 sX[F4_PER_ROW];   // 32 KB: preds row
    __shared__ float partials[4][5];

    const int row  = blockIdx.x;
    const int tid  = threadIdx.x;
    const int w    = tid >> 6;
    const int lane = tid & 63;

    const vfloat4* p4 = reinterpret_cast<const vfloat4*>(preds  + (size_t)row * N_COLS);
    const vfloat4* l4 = reinterpret_cast<const vfloat4*>(labels + (size_t)row * N_COLS);

    // ---- Phase 1: stage preds row into LDS. Single global stream. ----
    // Wave w covers float4 indices [w*512, (w+1)*512): contiguous 8 KB runs.
    #pragma unroll
    for (int i = 0; i < VPT; ++i) {
        const int g = (w << 9) + (i << 6) + lane;
        const vfloat4 x = __builtin_nontemporal_load(p4 + g);
        sX[g] = *reinterpret_cast<const float4*>(&x);   // ds_write_b128
    }
    __syncthreads();

    // ---- Phase 2: stream labels row; dot against LDS preds. ----
    float sx = 0.f, sy = 0.f, sxy = 0.f, sxx = 0.f, syy = 0.f;
    #pragma unroll
    for (int i = 0; i < VPT; ++i) {
        const int g = (w << 9) + (i << 6) + lane;
        const vfloat4 y = __builtin_nontemporal_load(l4 + g);
        const float4  a = sX[g];                         // ds_read_b128
        sx  += a.x + a.y + a.z + a.w;
        sy  += y.x + y.y + y.z + y.w;
        sxy += a.x * y.x + a.y * y.y + a.z * y.z + a.w * y.w;
        sxx += a.x * a.x + a.y * a.y + a.z * a.z + a.w * a.w;
        syy += y.x * y.x + y.y * y.y + y.z * y.z + y.w * y.w;
    }

    // 64-lane wave reduction (wave = 64 on gfx950).
    #pragma unroll
    for (int off = 32; off > 0; off >>= 1) {
        sx  += __shfl_down(sx,  off);
        sy  += __shfl_down(sy,  off);
        sxy += __shfl_down(sxy, off);
        sxx += __shfl_down(sxx, off);
        syy += __shfl_down(syy, off);
    }

    if (lane == 0) {
        partials[w][0] = sx;  partials[w][1] = sy;  partials[w][2] = sxy;
        partials[w][3] = sxx; partials[w][4] = syy;
    }
    __syncthreads();

    if (tid == 0) {
        float tx = 0.f, ty = 0.f, txy = 0.f, txx = 0.f, tyy = 0.f;
        #pragma unroll
        for (int v = 0; v < 4; ++v) {
            tx  += partials[v][0]; ty  += partials[v][1]; txy += partials[v][2];
            txx += partials[v][3]; tyy += partials[v][4];
        }
        const float Nf  = (float)N_COLS;
        const float num = Nf * txy - tx * ty;
        const float den = sqrtf((Nf * txx - tx * tx) * (Nf * tyy - ty * ty));
        row_loss[row] = 1.0f - num / den;
    }
}

// Reduce 4096 per-row losses to the mean. Single block.
__global__ __launch_bounds__(BLOCK) void mean_kernel(
    const float* __restrict__ row_loss,
    float* __restrict__ out)
{
    const int tid = threadIdx.x;

    float s = 0.f;
    #pragma unroll
    for (int i = 0; i < B_ROWS / BLOCK; ++i)
        s += row_loss[tid + i * BLOCK];

    #pragma unroll
    for (int off = 32; off > 0; off >>= 1)
        s += __shfl_down(s, off);

    __shared__ float smem[4];
    const int wave = tid >> 6;
    const int lane = tid & 63;
    if (lane == 0) smem[wave] = s;
    __syncthreads();

    if (tid == 0) {
        float t = smem[0] + smem[1] + smem[2] + smem[3];
        out[0] = t / (float)B_ROWS;
    }
}

extern "C" void kernel_launch(void* const* d_in, const int* in_sizes, int n_in,
                              void* d_out, int out_size, void* d_ws, size_t ws_size,
                              hipStream_t stream) {
    const float* preds  = (const float*)d_in[0];
    const float* labels = (const float*)d_in[1];
    float* row_loss = (float*)d_ws;      // 4096 floats of scratch
    float* out      = (float*)d_out;

    row_pearson_kernel<<<B_ROWS, BLOCK, 0, stream>>>(preds, labels, row_loss);
    mean_kernel<<<1, BLOCK, 0, stream>>>(row_loss, out);
}